// Round 3
// baseline (121718.994 us; speedup 1.0000x reference)
//
#include <hip/hip_runtime.h>

typedef _Float16 half2_t __attribute__((ext_vector_type(2)));
typedef unsigned uint_t;

#define B_    32
#define TE_   256
#define TD_   256
#define ENC_  512
#define HID_  1024
#define ATT_  128
#define OUT_  80
#define PRE_  256

// output regions (floats)
#define LOG_OFF  655360u
#define ATTW_OFF 663552u

// workspace offsets (float units)
#define OFF_PM    0u         // [32][128][256] f32
#define OFF_P1    1048576u   // [256][32][256] f32
#define OFF_M     3145728u   // [128*31] f32
#define OFF_WWH   3149824u   // [128][512] uint (fp16x2 of Ww)
#define OFF_XC0   3215360u   // [32][1408] uint: [ac 256|p1 128|h0_e 512|h0_o 512]
#define OFF_XC1   3260416u   // [32][1024] uint: [h1_e 512|h1_o 512]
#define OFF_C0    3293184u   // [1024][32] f32
#define OFF_C1    3325952u   // [1024][32] f32
#define OFF_CUM   3358720u   // [32][256] f32
#define OFF_ATTC  3366912u   // [3][32][512] f32
#define OFF_BAR   3416064u   // uint flags[256], go at [384]
#define OFF_END   3416576u

__device__ __forceinline__ float rcp_f(float x){ return __builtin_amdgcn_rcpf(x); }
__device__ __forceinline__ float sigm(float x){ return rcp_f(1.0f + __expf(-x)); }
__device__ __forceinline__ float tanh_f(float x){ float e = __expf(2.0f*x); return 1.0f - 2.0f*rcp_f(e+1.0f); }

__device__ __forceinline__ uint_t packh2(float a, float b){
  half2_t h; h[0] = (_Float16)a; h[1] = (_Float16)b;
  return __builtin_bit_cast(uint_t, h);
}
__device__ __forceinline__ float dot2f(uint_t w, uint_t x, float c){
#if __has_builtin(__builtin_amdgcn_fdot2)
  return __builtin_amdgcn_fdot2(__builtin_bit_cast(half2_t, w),
                                __builtin_bit_cast(half2_t, x), c, false);
#else
  half2_t a = __builtin_bit_cast(half2_t, w), b = __builtin_bit_cast(half2_t, x);
  return c + (float)a[0]*(float)b[0] + (float)a[1]*(float)b[1];
#endif
}

// reduce 32 items over 64 lanes; on return lane L (L<32 with +xor32 fold) holds item (L&31)
__device__ __forceinline__ void redsum32(float* v, int lane){
  #pragma unroll
  for (int s = 0; s < 5; ++s){
    const int d = 16 >> s;
    #pragma unroll
    for (int j = 0; j < 16; ++j){
      if (j < d){
        bool up = (lane & d) != 0;
        float give = up ? v[j] : v[j+d];
        float keep = up ? v[j+d] : v[j];
        v[j] = keep + __shfl_xor(give, d);
      }
    }
  }
  v[0] += __shfl_xor(v[0], 32);
}

// ---------------- one-time kernels ----------------

__global__ void k_init(float* __restrict__ ws){
  unsigned n = OFF_END - OFF_XC0;
  for (unsigned i = blockIdx.x*blockDim.x + threadIdx.x; i < n; i += gridDim.x*blockDim.x)
    ws[OFF_XC0 + i] = 0.f;
}

__global__ void k_precm(const float* __restrict__ Uw, const float* __restrict__ Fw,
                        float* __restrict__ ws){
  float* M = ws + OFF_M;
  for (int idx = threadIdx.x; idx < 128*31; idx += blockDim.x){
    int a = idx / 31, k = idx % 31;
    float s = 0.f;
    for (int c = 0; c < 32; c++) s += Uw[a*32+c]*Fw[c*31+k];
    M[idx] = s;
  }
}

__global__ void k_cvtww(const float* __restrict__ Ww, float* __restrict__ ws){
  uint_t* WWH = (uint_t*)(ws + OFF_WWH);
  int a = blockIdx.x;
  for (int p = threadIdx.x; p < 512; p += blockDim.x)
    WWH[a*512 + p] = packh2(Ww[a*1024 + 2*p], Ww[a*1024 + 2*p + 1]);
}

// processed_memory TRANSPOSED: pm[b][a][s]
__global__ __launch_bounds__(256) void k_pm(const float* __restrict__ enc,
    const float* __restrict__ Vw, const float* __restrict__ Vb, float* __restrict__ ws){
  float* pm = ws + OFF_PM;
  int b  = blockIdx.x >> 2;
  int s0 = (blockIdx.x & 3) << 6;
  int a  = threadIdx.x & 127;
  int sh = threadIdx.x >> 7;
  __shared__ float Vl[128*65];
  __shared__ float El[64*64];
  float acc[32];
  #pragma unroll
  for (int i=0;i<32;i++) acc[i]=0.f;
  for (int kc=0; kc<ENC_; kc+=64){
    for (int i=threadIdx.x; i<128*64; i+=256){
      int aa = i>>6, kk = i&63;
      Vl[aa*65+kk] = Vw[aa*ENC_ + kc + kk];
    }
    for (int i=threadIdx.x; i<64*64; i+=256){
      int ss = i>>6, kk = i&63;
      El[i] = enc[(size_t)(b*TE_ + s0 + ss)*ENC_ + kc + kk];
    }
    __syncthreads();
    for (int k=0;k<64;k++){
      float va = Vl[a*65+k];
      const float* er = &El[(sh*32)*64 + k];
      #pragma unroll
      for (int s=0;s<32;s++) acc[s] += va * er[s*64];
    }
    __syncthreads();
  }
  float bb = Vb[a];
  for (int s=0;s<32;s++)
    pm[((size_t)b*128 + a)*256 + (s0 + sh*32 + s)] = acc[s] + bb;
}

// fused prenet (both layers), writes P1 fp32
__global__ __launch_bounds__(256) void k_pre(const float* __restrict__ tgt,
    const float* __restrict__ w0, const float* __restrict__ b0,
    const float* __restrict__ w1, const float* __restrict__ b1,
    const float* __restrict__ masks, float* __restrict__ ws){
  float* P1 = ws + OFF_P1;
  int t = blockIdx.x, j = threadIdx.x;
  __shared__ float xl[32*80];
  __shared__ float p0l[32*256];
  for (int i=j; i<32*80; i+=256){
    int b = i/80, o = i%80;
    xl[i] = (t==0) ? 0.f : tgt[((size_t)b*TD_ + (t-1))*80 + o];
  }
  __syncthreads();
  {
    float bj = b0[j];
    float w[80];
    #pragma unroll
    for (int o=0;o<80;o++) w[o] = w0[j*80+o];
    for (int b=0;b<32;b++){
      float a0=0,a1=0,a2=0,a3=0;
      const float* x = &xl[b*80];
      #pragma unroll
      for (int o=0;o<80;o+=4){
        a0+=w[o]*x[o]; a1+=w[o+1]*x[o+1]; a2+=w[o+2]*x[o+2]; a3+=w[o+3]*x[o+3];
      }
      float m = masks[(((size_t)t*2+0)*32+b)*256 + j];
      p0l[b*256 + j] = fmaxf(bj+a0+a1+a2+a3, 0.f) * m;
    }
  }
  __syncthreads();
  {
    float bj = b1[j];
    const float4* wr = (const float4*)(w1 + j*256);
    float acc[32];
    #pragma unroll
    for (int i=0;i<32;i++) acc[i]=0.f;
    for (int o4=0;o4<64;o4++){
      float4 w = wr[o4];
      #pragma unroll
      for (int b=0;b<32;b++){
        const float4 xv = *(const float4*)&p0l[b*256 + o4*4];
        acc[b] += w.x*xv.x + w.y*xv.y + w.z*xv.z + w.w*xv.w;
      }
    }
    for (int b=0;b<32;b++){
      float m = masks[(((size_t)t*2+1)*32+b)*256 + j];
      P1[((size_t)t*32 + b)*256 + j] = fmaxf(bj+acc[b], 0.f) * m;
    }
  }
}

// ---------------- persistent decode kernel ----------------

__device__ __forceinline__ void gbar(uint_t* flags, uint_t* go, int bid, int tid, int c){
  __syncthreads();
  if (bid == 96){
    if (tid < 256 && tid != 96){
      while (__hip_atomic_load(&flags[tid], __ATOMIC_ACQUIRE, __HIP_MEMORY_SCOPE_AGENT) < (uint_t)c)
        __builtin_amdgcn_s_sleep(2);
    }
    __syncthreads();
    if (tid == 0){
      __threadfence();
      __hip_atomic_store(go, (uint_t)c, __ATOMIC_RELEASE, __HIP_MEMORY_SCOPE_AGENT);
    }
    __syncthreads();
  } else {
    if (tid == 0){
      __threadfence();
      __hip_atomic_store(&flags[bid], (uint_t)c, __ATOMIC_RELEASE, __HIP_MEMORY_SCOPE_AGENT);
      while (__hip_atomic_load(go, __ATOMIC_ACQUIRE, __HIP_MEMORY_SCOPE_AGENT) < (uint_t)c)
        __builtin_amdgcn_s_sleep(2);
      __threadfence();
    }
    __syncthreads();
  }
}

__global__ __launch_bounds__(512, 2) void k_main(
    const float* __restrict__ enc, const int* __restrict__ lens,
    const float* __restrict__ ww, const float* __restrict__ wb,
    const float* __restrict__ l0wih, const float* __restrict__ l0whh,
    const float* __restrict__ l0bih, const float* __restrict__ l0bhh,
    const float* __restrict__ l1wih, const float* __restrict__ l1whh,
    const float* __restrict__ l1bih, const float* __restrict__ l1bhh,
    const float* __restrict__ featw, const float* __restrict__ probw,
    const float* __restrict__ probb,
    float* __restrict__ ws, float* __restrict__ out)
{
  __shared__ __align__(16) uint_t smem[37120];
  const int bid = blockIdx.x, tid = threadIdx.x;
  const int lane = tid & 63;
  const int rg = tid >> 6;          // wave id = rowgroup
  const int ks = lane;              // k-slice
  const bool isL0 = bid < 128;

  float* PM  = ws + OFF_PM;
  float* P1  = ws + OFF_P1;
  float* Mg  = ws + OFF_M;
  uint_t* WWH = (uint_t*)(ws + OFF_WWH);
  uint_t* XC0 = (uint_t*)(ws + OFF_XC0);
  uint_t* XC1 = (uint_t*)(ws + OFF_XC1);
  _Float16* XC0h = (_Float16*)XC0;
  _Float16* XC1h = (_Float16*)XC1;
  float* C0  = ws + OFF_C0;
  float* C1  = ws + OFF_C1;
  float* CUM = ws + OFF_CUM;
  float* ATTC = ws + OFF_ATTC;
  uint_t* BARf = (uint_t*)(ws + OFF_BAR);
  uint_t* BARg = BARf + 384;

  uint_t* xl   = smem;                         // L0: 28672, L1: 32768
  float* gsumf = (float*)(smem + 28672);       // [4][8][32] (L0)
  float* Ml    = (float*)(smem + 29696);       // [128][32]
  float* apad  = (float*)(smem + 33792);       // 320
  float* whl   = (float*)(smem + 34112);       // 128
  float* wl    = (float*)(smem + 34240);       // 128
  float* scl   = (float*)(smem + 34368);       // 256
  float* awl   = (float*)(smem + 34624);       // 256
  float* redl  = (float*)(smem + 34880);       // 128
  float* psq   = (float*)(smem + 35008);       // 2048
  float* gsum1 = (float*)(smem + 32768);       // [4][8][32] (L1)
  float* redo  = (float*)(smem + 33792);       // 512 (L1 out blocks)

  // ---- load resident weights (fp16 pairs) ----
  uint_t wp[4][16];
  float bsum[4];
  const int ublk = isL0 ? bid*8 : (bid-128)*8;
  if (isL0){
    #pragma unroll
    for (int rr=0; rr<4; rr++){
      int grow = (rg&3)*1024 + ublk + (rg>>2)*4 + rr;
      #pragma unroll
      for (int jp=0; jp<14; jp++){
        int k = (ks*14 + jp)*2;
        const float* src = (k < 768) ? (l0wih + (size_t)grow*768 + k)
                                     : (l0whh + (size_t)grow*1024 + (k-768));
        wp[rr][jp] = packh2(src[0], src[1]);
      }
      wp[rr][14] = 0; wp[rr][15] = 0;
    }
  } else {
    #pragma unroll
    for (int rr=0; rr<4; rr++){
      int grow = (rg&3)*1024 + ublk + (rg>>2)*4 + rr;
      #pragma unroll
      for (int jp=0; jp<16; jp++){
        int k = (ks*16 + jp)*2;
        const float* src = (k < 1024) ? (l1wih + (size_t)grow*1024 + k)
                                      : (l1whh + (size_t)grow*1024 + (k-1024));
        wp[rr][jp] = packh2(src[0], src[1]);
      }
    }
  }
  if (tid < 256){
    int uloc = tid >> 5, b_ = tid & 31; (void)b_;
    int u = ublk + uloc;
    const float* bi = isL0 ? l0bih : l1bih;
    const float* bh = isL0 ? l0bhh : l1bhh;
    #pragma unroll
    for (int g=0; g<4; g++) bsum[g] = bi[g*1024+u] + bh[g*1024+u];
  }
  int xoff1[8];
  {
    int swz = ((ks>>1)&7) << 1;
    #pragma unroll
    for (int j=0;j<8;j++) xoff1[j] = (ks*16 + j*2) ^ swz;
  }

  int barc = 0;
  for (int tau = 0; tau < 258; ++tau){
    const int pcur = tau & 1, pprev = pcur ^ 1;

    // ================= PHASE A =================
    if (isL0){
      if (tau < 256){
        { // stage h0(tau-1) -> xl cols 384..895
          int sb = tid >> 4, seg = tid & 15;
          const uint_t* src = XC0 + sb*1408 + 384 + pprev*512;
          uint_t* dst = xl + sb*896 + 384;
          #pragma unroll
          for (int q=0;q<8;q++){
            int c = seg*4 + q*64;
            *(uint4*)(dst + c) = *(const uint4*)(src + c);
          }
        }
        if (bid < 32){
          const int b = bid;
          const int len = lens[b];
          __syncthreads();
          // ---- Wh = Ww . h0(tau-1)  (fp16 dot2) ----
          {
            int ag = tid >> 4, l16 = tid & 15;
            float wv0=0, wv1=0, wv2=0, wv3=0;
            const uint_t* xb = xl + b*896 + 384;
            for (int q=0;q<32;q++){
              uint_t xv = xb[l16 + q*16];
              wv0 = dot2f(WWH[(ag*4+0)*512 + l16 + q*16], xv, wv0);
              wv1 = dot2f(WWH[(ag*4+1)*512 + l16 + q*16], xv, wv1);
              wv2 = dot2f(WWH[(ag*4+2)*512 + l16 + q*16], xv, wv2);
              wv3 = dot2f(WWH[(ag*4+3)*512 + l16 + q*16], xv, wv3);
            }
            float v0, v1;
            { bool up = (l16 & 8) != 0;
              float g0 = up ? wv0 : wv2, k0 = up ? wv2 : wv0;
              float g1 = up ? wv1 : wv3, k1 = up ? wv3 : wv1;
              v0 = k0 + __shfl_xor(g0, 8);
              v1 = k1 + __shfl_xor(g1, 8); }
            { bool up = (l16 & 4) != 0;
              float g = up ? v0 : v1, k = up ? v1 : v0;
              v0 = k + __shfl_xor(g, 4); }
            v0 += __shfl_xor(v0, 2);
            v0 += __shfl_xor(v0, 1);
            if ((l16 & 3) == 0) whl[ag*4 + (l16>>2)] = v0;
          }
          for (int i=tid; i<128*31; i+=512) Ml[(i/31)*32 + (i%31)] = Mg[i];
          for (int i=tid; i<288; i+=512){
            int p = i - 15;
            float vv = 0.f;
            if (p >= 0 && p < 256)
              vv = (tau==0) ? ((p < len) ? 1.0f/(float)len : 0.f) : CUM[b*256 + p];
            apad[i] = vv;
          }
          if (tid < 128) wl[tid] = ww[tid];
          __syncthreads();
          // ---- scores ----
          {
            int pg = tid & 63, q = tid >> 6;
            float apw[36];
            #pragma unroll
            for (int i=0;i<36;i+=4) *(float4*)&apw[i] = *(const float4*)&apad[pg*4 + i];
            float part0=0, part1=0, part2=0, part3=0;
            const float* pmb = PM + (size_t)b*128*256;
            for (int aa=0; aa<16; aa++){
              int a = q*16 + aa;
              const float* mr = Ml + a*32;
              float4 pv = *(const float4*)(pmb + (size_t)a*256 + pg*4);
              float wa = whl[a];
              float u0 = pv.x + wa, u1 = pv.y + wa, u2 = pv.z + wa, u3 = pv.w + wa;
              #pragma unroll
              for (int k=0;k<28;k+=4){
                float4 m4 = *(const float4*)(mr + k);
                u0 += m4.x*apw[k]   + m4.y*apw[k+1] + m4.z*apw[k+2] + m4.w*apw[k+3];
                u1 += m4.x*apw[k+1] + m4.y*apw[k+2] + m4.z*apw[k+3] + m4.w*apw[k+4];
                u2 += m4.x*apw[k+2] + m4.y*apw[k+3] + m4.z*apw[k+4] + m4.w*apw[k+5];
                u3 += m4.x*apw[k+3] + m4.y*apw[k+4] + m4.z*apw[k+5] + m4.w*apw[k+6];
              }
              float m28 = mr[28], m29 = mr[29], m30 = mr[30];
              u0 += m28*apw[28] + m29*apw[29] + m30*apw[30];
              u1 += m28*apw[29] + m29*apw[30] + m30*apw[31];
              u2 += m28*apw[30] + m29*apw[31] + m30*apw[32];
              u3 += m28*apw[31] + m29*apw[32] + m30*apw[33];
              float wv = wl[a];
              part0 += tanh_f(u0)*wv; part1 += tanh_f(u1)*wv;
              part2 += tanh_f(u2)*wv; part3 += tanh_f(u3)*wv;
            }
            float4 pp; pp.x = part0; pp.y = part1; pp.z = part2; pp.w = part3;
            *(float4*)&psq[tid*4] = pp;
          }
          __syncthreads();
          if (tid < 256){
            float s = wb[0];
            int pgg = tid >> 2, d = tid & 3;
            #pragma unroll
            for (int qq=0;qq<8;qq++) s += psq[(qq*64 + pgg)*4 + d];
            scl[tid] = (tid >= len) ? -1.0e9f : s;
          }
          __syncthreads();
          if (tid < 128) redl[tid] = fmaxf(scl[tid], scl[tid+128]);
          __syncthreads();
          if (tid < 64){
            float v = fmaxf(redl[tid], redl[tid+64]);
            #pragma unroll
            for (int off=32; off>0; off>>=1) v = fmaxf(v, __shfl_down(v, off));
            if (tid==0) redl[0] = v;
          }
          __syncthreads();
          float mx = redl[0];
          if (tid < 256) awl[tid] = __expf(scl[tid]-mx);
          __syncthreads();
          if (tid < 128) redl[tid] = awl[tid] + awl[tid+128];
          __syncthreads();
          if (tid < 64){
            float v = redl[tid] + redl[tid+64];
            #pragma unroll
            for (int off=32; off>0; off>>=1) v += __shfl_down(v, off);
            if (tid==0) redl[0] = v;
          }
          __syncthreads();
          float inv = rcp_f(redl[0]);
          if (tid < 256){
            float aw = awl[tid]*inv;
            awl[tid] = aw;
            CUM[b*256 + tid] += aw;
            out[ATTW_OFF + ((size_t)b*TD_ + tau)*256 + tid] = aw;
          }
          __syncthreads();
          // ---- context ----
          {
            int el = tid & 127, ph = tid >> 7;
            const float* ep = enc + ((size_t)b*256 + ph*64)*512 + el*4;
            float4 ca; ca.x=0; ca.y=0; ca.z=0; ca.w=0;
            for (int p=0;p<64;p++){
              float a = awl[ph*64 + p];
              float4 ev = *(const float4*)(ep + (size_t)p*512);
              ca.x += a*ev.x; ca.y += a*ev.y; ca.z += a*ev.z; ca.w += a*ev.w;
            }
            *(float4*)&psq[(ph*128 + el)*4] = ca;
          }
          __syncthreads();
          if (tid < 128){
            float4 s = *(const float4*)&psq[tid*4];
            #pragma unroll
            for (int g=1; g<4; g++){
              float4 o = *(const float4*)&psq[(g*128+tid)*4];
              s.x+=o.x; s.y+=o.y; s.z+=o.z; s.w+=o.w;
            }
            *(float4*)(ATTC + (size_t)(tau%3)*16384 + b*512 + tid*4) = s;
            XC0[b*1408 + tid*2]     = packh2(s.x, s.y);
            XC0[b*1408 + tid*2 + 1] = packh2(s.z, s.w);
            // prenet p1 -> fp16
            float2 pv = *(const float2*)(P1 + ((size_t)tau*32 + b)*256 + tid*2);
            XC0[b*1408 + 256 + tid] = packh2(pv.x, pv.y);
          }
        }
      }
    } else {
      const int ob = bid - 128;
      if (ob < 24 && tau >= 2){
        const int tt = tau - 2;
        int b = tid & 31, rr = (tid>>5)&3, ksq = tid>>7;
        int r = ob*4 + rr;
        const float* wr = (r < 80) ? (featw + (size_t)r*1536) : probw;
        const float* acp = ATTC + (size_t)(tt%3)*16384 + b*512;
        float acc = 0.f;
        for (int j=0;j<96;j++){
          int k = ksq*384 + j*4;
          float x0,x1,x2,x3;
          if (k < 1024){
            uint2 hw = *(const uint2*)(XC1 + b*1024 + pcur*512 + (k>>1));
            half2_t ha = __builtin_bit_cast(half2_t, hw.x);
            half2_t hb = __builtin_bit_cast(half2_t, hw.y);
            x0 = (float)ha[0]; x1 = (float)ha[1]; x2 = (float)hb[0]; x3 = (float)hb[1];
          } else {
            float4 f = *(const float4*)(acp + (k-1024));
            x0 = f.x; x1 = f.y; x2 = f.z; x3 = f.w;
          }
          if (r <= 80){
            float4 wv = *(const float4*)(wr + k);
            acc += wv.x*x0 + wv.y*x1 + wv.z*x2 + wv.w*x3;
          }
        }
        redo[(rr*4+ksq)*32 + b] = acc;
        __syncthreads();
        if (tid < 128){
          int b2 = tid&31, r2 = tid>>5;
          float vsum = redo[(r2*4+0)*32+b2] + redo[(r2*4+1)*32+b2]
                     + redo[(r2*4+2)*32+b2] + redo[(r2*4+3)*32+b2];
          int rr2 = ob*4 + r2;
          if (rr2 < 80)       out[((size_t)b2*80 + rr2)*256 + tt] = vsum;
          else if (rr2 == 80) out[LOG_OFF + (size_t)b2*256 + tt] = vsum + probb[0];
        }
        __syncthreads();
      }
      if (tau >= 1 && tau <= 256){
        // stage x1 = [h0(tau-1) | h1(tau-2)] fp16, swizzled
        int sb = tid >> 4, seg = tid & 15;
        uint_t* dst = xl + sb*1024;
        #pragma unroll
        for (int q=0;q<16;q++){
          int c = seg*4 + q*64;
          uint4 v;
          if (c < 512) v = *(const uint4*)(XC0 + sb*1408 + 384 + pprev*512 + c);
          else         v = *(const uint4*)(XC1 + sb*1024 + pcur*512 + (c-512));
          int m = ((c>>5)&7) << 1;
          uint2 lo; lo.x = v.x; lo.y = v.y;
          uint2 hi; hi.x = v.z; hi.y = v.w;
          *(uint2*)(dst + (c^m))     = lo;
          *(uint2*)(dst + ((c+2)^m)) = hi;
        }
      }
    }
    gbar(BARf, BARg, bid, tid, ++barc);

    // ================= PHASE B =================
    if (isL0){
      if (tau < 256){
        { // stage ac|p1 -> xl cols 0..383
          int sb = tid >> 4, seg = tid & 15;
          const uint_t* src = XC0 + sb*1408;
          uint_t* dst = xl + sb*896;
          #pragma unroll
          for (int q=0;q<6;q++){
            int c = seg*4 + q*64;
            *(uint4*)(dst + c) = *(const uint4*)(src + c);
          }
        }
        __syncthreads();
        // lstm0: 32 rows x K=1792
        #pragma unroll 1
        for (int bg=0; bg<4; bg++){
          float v[32];
          #pragma unroll
          for (int i=0;i<32;i++) v[i]=0.f;
          #pragma unroll
          for (int b8=0;b8<8;b8++){
            const uint_t* xp = xl + (bg*8+b8)*896 + ks*14;
            uint2 x0 = *(const uint2*)(xp+0);
            uint2 x1 = *(const uint2*)(xp+2);
            uint2 x2 = *(const uint2*)(xp+4);
            uint2 x3 = *(const uint2*)(xp+6);
            uint2 x4 = *(const uint2*)(xp+8);
            uint2 x5 = *(const uint2*)(xp+10);
            uint2 x6 = *(const uint2*)(xp+12);
            #pragma unroll
            for (int rr=0;rr<4;rr++){
              float a = v[rr*8+b8];
              a = dot2f(wp[rr][0],  x0.x, a); a = dot2f(wp[rr][1],  x0.y, a);
              a = dot2f(wp[rr][2],  x1.x, a); a = dot2f(wp[rr][3],  x1.y, a);
              a = dot2f(wp[rr][4],  x2.x, a); a = dot2f(wp[rr][5],  x2.y, a);
              a = dot2f(wp[rr][6],  x3.x, a); a = dot2f(wp[rr][7],  x3.y, a);
              a = dot2f(wp[rr][8],  x4.x, a); a = dot2f(wp[rr][9],  x4.y, a);
              a = dot2f(wp[rr][10], x5.x, a); a = dot2f(wp[rr][11], x5.y, a);
              a = dot2f(wp[rr][12], x6.x, a); a = dot2f(wp[rr][13], x6.y, a);
              v[rr*8+b8] = a;
            }
          }
          redsum32(v, lane);
          if (lane < 32)
            gsumf[(rg&3)*256 + ((rg>>2)*4 + (lane>>3))*32 + bg*8 + (lane&7)] = v[0];
        }
        __syncthreads();
        if (tid < 256){
          int uloc = tid >> 5, b = tid & 31;
          int u = ublk + uloc;
          float gi = gsumf[0*256 + uloc*32 + b] + bsum[0];
          float gf = gsumf[1*256 + uloc*32 + b] + bsum[1];
          float gg = gsumf[2*256 + uloc*32 + b] + bsum[2];
          float go_ = gsumf[3*256 + uloc*32 + b] + bsum[3];
          float c_old = C0[u*32 + b];
          uint_t hw = xl[b*896 + 384 + (u>>1)];
          half2_t hh = __builtin_bit_cast(half2_t, hw);
          float h_old = (float)hh[u&1];
          float cn = sigm(gf)*c_old + sigm(gi)*tanh_f(gg);
          float hn = sigm(go_)*tanh_f(cn);
          C0[u*32 + b] = 0.1f*c_old + 0.9f*cn;
          float hz = 0.1f*h_old + 0.9f*hn;
          XC0h[b*2816 + 768 + pcur*1024 + u] = (_Float16)hz;
        }
      }
    } else {
      if (tau >= 1 && tau <= 256){
        // lstm1(tau-1): 32 rows x K=2048
        #pragma unroll 1
        for (int bg=0; bg<4; bg++){
          float v[32];
          #pragma unroll
          for (int i=0;i<32;i++) v[i]=0.f;
          #pragma unroll
          for (int b8=0;b8<8;b8++){
            const uint_t* xp = xl + (bg*8+b8)*1024;
            uint2 x0 = *(const uint2*)(xp + xoff1[0]);
            uint2 x1 = *(const uint2*)(xp + xoff1[1]);
            uint2 x2 = *(const uint2*)(xp + xoff1[2]);
            uint2 x3 = *(const uint2*)(xp + xoff1[3]);
            uint2 x4 = *(const uint2*)(xp + xoff1[4]);
            uint2 x5 = *(const uint2*)(xp + xoff1[5]);
            uint2 x6 = *(const uint2*)(xp + xoff1[6]);
            uint2 x7 = *(const uint2*)(xp + xoff1[7]);
            #pragma unroll
            for (int rr=0;rr<4;rr++){
              float a = v[rr*8+b8];
              a = dot2f(wp[rr][0],  x0.x, a); a = dot2f(wp[rr][1],  x0.y, a);
              a = dot2f(wp[rr][2],  x1.x, a); a = dot2f(wp[rr][3],  x1.y, a);
              a = dot2f(wp[rr][4],  x2.x, a); a = dot2f(wp[rr][5],  x2.y, a);
              a = dot2f(wp[rr][6],  x3.x, a); a = dot2f(wp[rr][7],  x3.y, a);
              a = dot2f(wp[rr][8],  x4.x, a); a = dot2f(wp[rr][9],  x4.y, a);
              a = dot2f(wp[rr][10], x5.x, a); a = dot2f(wp[rr][11], x5.y, a);
              a = dot2f(wp[rr][12], x6.x, a); a = dot2f(wp[rr][13], x6.y, a);
              a = dot2f(wp[rr][14], x7.x, a); a = dot2f(wp[rr][15], x7.y, a);
              v[rr*8+b8] = a;
            }
          }
          redsum32(v, lane);
          if (lane < 32)
            gsum1[(rg&3)*256 + ((rg>>2)*4 + (lane>>3))*32 + bg*8 + (lane&7)] = v[0];
        }
        __syncthreads();
        if (tid < 256){
          int uloc = tid >> 5, b = tid & 31;
          int u = ublk + uloc;
          float gi = gsum1[0*256 + uloc*32 + b] + bsum[0];
          float gf = gsum1[1*256 + uloc*32 + b] + bsum[1];
          float gg = gsum1[2*256 + uloc*32 + b] + bsum[2];
          float go_ = gsum1[3*256 + uloc*32 + b] + bsum[3];
          float c_old = C1[u*32 + b];
          int cs = 512 + (u>>1);
          uint_t hw = xl[b*1024 + (cs ^ (((cs>>5)&7)<<1))];
          half2_t hh = __builtin_bit_cast(half2_t, hw);
          float h_old = (float)hh[u&1];
          float cn = sigm(gf)*c_old + sigm(gi)*tanh_f(gg);
          float hn = sigm(go_)*tanh_f(cn);
          C1[u*32 + b] = 0.1f*c_old + 0.9f*cn;
          float hz = 0.1f*h_old + 0.9f*hn;
          XC1h[b*2048 + pprev*1024 + u] = (_Float16)hz;
        }
      }
    }
    gbar(BARf, BARg, bid, tid, ++barc);
  }
}

extern "C" void kernel_launch(void* const* d_in, const int* in_sizes, int n_in,
                              void* d_out, int out_size, void* d_ws, size_t ws_size,
                              hipStream_t stream){
  const float* enc   = (const float*)d_in[0];
  const float* tgt   = (const float*)d_in[1];
  const float* masks = (const float*)d_in[2];
  const int*   lens  = (const int*)  d_in[3];
  const float* Vw    = (const float*)d_in[4];
  const float* Vb    = (const float*)d_in[5];
  const float* Ww    = (const float*)d_in[6];
  const float* Uw    = (const float*)d_in[7];
  const float* Fw    = (const float*)d_in[8];
  const float* ww    = (const float*)d_in[9];
  const float* wb    = (const float*)d_in[10];
  const float* pw0   = (const float*)d_in[11];
  const float* pb0   = (const float*)d_in[12];
  const float* pw1   = (const float*)d_in[13];
  const float* pb1   = (const float*)d_in[14];
  const float* l0wih = (const float*)d_in[15];
  const float* l0whh = (const float*)d_in[16];
  const float* l0bih = (const float*)d_in[17];
  const float* l0bhh = (const float*)d_in[18];
  const float* l1wih = (const float*)d_in[19];
  const float* l1whh = (const float*)d_in[20];
  const float* l1bih = (const float*)d_in[21];
  const float* l1bhh = (const float*)d_in[22];
  const float* featw = (const float*)d_in[23];
  const float* probw = (const float*)d_in[24];
  const float* probb = (const float*)d_in[25];
  float* ws  = (float*)d_ws;
  float* out = (float*)d_out;

  k_init <<<256,256,0,stream>>>(ws);
  k_pre  <<<256,256,0,stream>>>(tgt, pw0, pb0, pw1, pb1, masks, ws);
  k_precm<<<1,  256,0,stream>>>(Uw, Fw, ws);
  k_cvtww<<<128,256,0,stream>>>(Ww, ws);
  k_pm   <<<128,256,0,stream>>>(enc, Vw, Vb, ws);

  k_main<<<256,512,0,stream>>>(enc, lens, ww, wb,
                               l0wih, l0whh, l0bih, l0bhh,
                               l1wih, l1whh, l1bih, l1bhh,
                               featw, probw, probb, ws, out);
}

// Round 4
// 15558.412 us; speedup vs baseline: 7.8234x; 7.8234x over previous
//
#include <hip/hip_runtime.h>

typedef _Float16 half2_t __attribute__((ext_vector_type(2)));
typedef unsigned uint_t;

#define B_    32
#define TE_   256
#define TD_   256
#define ENC_  512
#define HID_  1024
#define ATT_  128
#define OUT_  80
#define PRE_  256

// output regions (floats)
#define LOG_OFF  655360u
#define ATTW_OFF 663552u

// workspace offsets (float units)
#define OFF_PM    0u          // [32][128][256] f32 (transposed pm)
#define OFF_P1H   1048576u    // [256][32][128] uint (fp16x2 prenet out)
#define OFF_M     2097152u    // [128*31] f32
#define OFF_WWH   2101248u    // [128][512] uint (fp16x2 Ww)
#define OFF_ENCH  2166784u    // [32][256][256] uint (fp16x2 enc)
#define OFF_W0P   4263936u    // [4096][896] uint (fp16x2 lstm0 w)
#define OFF_W1P   7933952u    // [4096][1024] uint (fp16x2 lstm1 w)
#define OFF_XC0   12128256u   // [32][1408] uint: [ac 256|p1 128|h0_e 512|h0_o 512]
#define OFF_XC1   12173312u   // [32][1024] uint: [h1_e 512|h1_o 512]
#define OFF_C0    12206080u   // [1024][32] f32
#define OFF_C1    12238848u   // [1024][32] f32
#define OFF_CUM   12271616u   // [32][256] f32
#define OFF_ATTC  12279808u   // [3][32][512] f32 ring
#define OFF_END   12328960u

__device__ __forceinline__ float rcp_f(float x){ return __builtin_amdgcn_rcpf(x); }
__device__ __forceinline__ float sigm(float x){ return rcp_f(1.0f + __expf(-x)); }
__device__ __forceinline__ float tanh_f(float x){ float e = __expf(2.0f*x); return 1.0f - 2.0f*rcp_f(e+1.0f); }

__device__ __forceinline__ uint_t packh2(float a, float b){
  half2_t h; h[0] = (_Float16)a; h[1] = (_Float16)b;
  return __builtin_bit_cast(uint_t, h);
}
__device__ __forceinline__ float dot2f(uint_t w, uint_t x, float c){
#if __has_builtin(__builtin_amdgcn_fdot2)
  return __builtin_amdgcn_fdot2(__builtin_bit_cast(half2_t, w),
                                __builtin_bit_cast(half2_t, x), c, false);
#else
  half2_t a = __builtin_bit_cast(half2_t, w), b = __builtin_bit_cast(half2_t, x);
  return c + (float)a[0]*(float)b[0] + (float)a[1]*(float)b[1];
#endif
}

// ---------------- one-time kernels ----------------

__global__ void k_init(float* __restrict__ ws){
  unsigned n = OFF_END - OFF_XC0;
  for (unsigned i = blockIdx.x*blockDim.x + threadIdx.x; i < n; i += gridDim.x*blockDim.x)
    ws[OFF_XC0 + i] = 0.f;
}

__global__ void k_precm(const float* __restrict__ Uw, const float* __restrict__ Fw,
                        float* __restrict__ ws){
  float* M = ws + OFF_M;
  for (int idx = threadIdx.x; idx < 128*31; idx += blockDim.x){
    int a = idx / 31, k = idx % 31;
    float s = 0.f;
    for (int c = 0; c < 32; c++) s += Uw[a*32+c]*Fw[c*31+k];
    M[idx] = s;
  }
}

__global__ void k_cvtww(const float* __restrict__ Ww, float* __restrict__ ws){
  uint_t* WWH = (uint_t*)(ws + OFF_WWH);
  int a = blockIdx.x;
  for (int p = threadIdx.x; p < 512; p += blockDim.x)
    WWH[a*512 + p] = packh2(Ww[a*1024 + 2*p], Ww[a*1024 + 2*p + 1]);
}

__global__ void k_packenc(const float* __restrict__ enc, float* __restrict__ ws){
  uint_t* ENCH = (uint_t*)(ws + OFF_ENCH);
  size_t row = blockIdx.x;           // b*256 + p, 8192 rows
  for (int j = threadIdx.x; j < 256; j += blockDim.x)
    ENCH[row*256 + j] = packh2(enc[row*512 + 2*j], enc[row*512 + 2*j + 1]);
}

// lstm0 weights: rows grow=g*1024+u, cols [wih 768 | whh 1024] -> 896 fp16-pairs
__global__ void k_packw0(const float* __restrict__ wih, const float* __restrict__ whh,
                         float* __restrict__ ws){
  uint_t* W = (uint_t*)(ws + OFF_W0P);
  size_t r = blockIdx.x;             // 4096 rows
  for (int p = threadIdx.x; p < 896; p += blockDim.x){
    int k = 2*p;
    const float* src = (k < 768) ? (wih + r*768 + k) : (whh + r*1024 + (k-768));
    W[r*896 + p] = packh2(src[0], src[1]);
  }
}

// lstm1 weights: rows grow, cols [wih 1024 | whh 1024] -> 1024 pairs
__global__ void k_packw1(const float* __restrict__ wih, const float* __restrict__ whh,
                         float* __restrict__ ws){
  uint_t* W = (uint_t*)(ws + OFF_W1P);
  size_t r = blockIdx.x;
  for (int p = threadIdx.x; p < 1024; p += blockDim.x){
    int k = 2*p;
    const float* src = (k < 1024) ? (wih + r*1024 + k) : (whh + r*1024 + (k-1024));
    W[r*1024 + p] = packh2(src[0], src[1]);
  }
}

// processed_memory TRANSPOSED: pm[b][a][s]
__global__ __launch_bounds__(256) void k_pm(const float* __restrict__ enc,
    const float* __restrict__ Vw, const float* __restrict__ Vb, float* __restrict__ ws){
  float* pm = ws + OFF_PM;
  int b  = blockIdx.x >> 2;
  int s0 = (blockIdx.x & 3) << 6;
  int a  = threadIdx.x & 127;
  int sh = threadIdx.x >> 7;
  __shared__ float Vl[128*65];
  __shared__ float El[64*64];
  float acc[32];
  #pragma unroll
  for (int i=0;i<32;i++) acc[i]=0.f;
  for (int kc=0; kc<ENC_; kc+=64){
    for (int i=threadIdx.x; i<128*64; i+=256){
      int aa = i>>6, kk = i&63;
      Vl[aa*65+kk] = Vw[aa*ENC_ + kc + kk];
    }
    for (int i=threadIdx.x; i<64*64; i+=256){
      int ss = i>>6, kk = i&63;
      El[i] = enc[(size_t)(b*TE_ + s0 + ss)*ENC_ + kc + kk];
    }
    __syncthreads();
    for (int k=0;k<64;k++){
      float va = Vl[a*65+k];
      const float* er = &El[(sh*32)*64 + k];
      #pragma unroll
      for (int s=0;s<32;s++) acc[s] += va * er[s*64];
    }
    __syncthreads();
  }
  float bb = Vb[a];
  for (int s=0;s<32;s++)
    pm[((size_t)b*128 + a)*256 + (s0 + sh*32 + s)] = acc[s] + bb;
}

// fused prenet (both layers), writes P1H fp16 pairs
__global__ __launch_bounds__(256) void k_pre(const float* __restrict__ tgt,
    const float* __restrict__ w0, const float* __restrict__ b0,
    const float* __restrict__ w1, const float* __restrict__ b1,
    const float* __restrict__ masks, float* __restrict__ ws){
  uint_t* P1H = (uint_t*)(ws + OFF_P1H);
  int t = blockIdx.x, j = threadIdx.x;
  __shared__ float xl[32*80];
  __shared__ float p0l[32*256];
  __shared__ float p1s[256*32];
  for (int i=j; i<32*80; i+=256){
    int b = i/80, o = i%80;
    xl[i] = (t==0) ? 0.f : tgt[((size_t)b*TD_ + (t-1))*80 + o];
  }
  __syncthreads();
  {
    float bj = b0[j];
    float w[80];
    #pragma unroll
    for (int o=0;o<80;o++) w[o] = w0[j*80+o];
    for (int b=0;b<32;b++){
      float a0=0,a1=0,a2=0,a3=0;
      const float* x = &xl[b*80];
      #pragma unroll
      for (int o=0;o<80;o+=4){
        a0+=w[o]*x[o]; a1+=w[o+1]*x[o+1]; a2+=w[o+2]*x[o+2]; a3+=w[o+3]*x[o+3];
      }
      float m = masks[(((size_t)t*2+0)*32+b)*256 + j];
      p0l[b*256 + j] = fmaxf(bj+a0+a1+a2+a3, 0.f) * m;
    }
  }
  __syncthreads();
  {
    float bj = b1[j];
    const float4* wr = (const float4*)(w1 + j*256);
    float acc[32];
    #pragma unroll
    for (int i=0;i<32;i++) acc[i]=0.f;
    for (int o4=0;o4<64;o4++){
      float4 w = wr[o4];
      #pragma unroll
      for (int b=0;b<32;b++){
        const float4 xv = *(const float4*)&p0l[b*256 + o4*4];
        acc[b] += w.x*xv.x + w.y*xv.y + w.z*xv.z + w.w*xv.w;
      }
    }
    for (int b=0;b<32;b++){
      float m = masks[(((size_t)t*2+1)*32+b)*256 + j];
      p1s[j*32 + b] = fmaxf(bj+acc[b], 0.f) * m;
    }
  }
  __syncthreads();
  for (int i=j; i<32*128; i+=256){
    int b = i >> 7, jp = i & 127;
    P1H[((size_t)t*32 + b)*128 + jp] = packh2(p1s[(2*jp)*32 + b], p1s[(2*jp+1)*32 + b]);
  }
}

// ---------------- per-step kernel A: attention(t) + outputs(t-2) ----------------

__global__ __launch_bounds__(512) void k_stepa(int t,
    const int* __restrict__ lens, const float* __restrict__ ww, const float* __restrict__ wb,
    const float* __restrict__ featw, const float* __restrict__ probw,
    const float* __restrict__ probb, float* __restrict__ ws, float* __restrict__ out){
  __shared__ __align__(16) uint_t h0l[512];
  __shared__ __align__(16) float Ml[128*32];
  __shared__ __align__(16) float apad[320];
  __shared__ __align__(16) float whl[128];
  __shared__ __align__(16) float wl[128];
  __shared__ __align__(16) float scl[256];
  __shared__ __align__(16) float awl[256];
  __shared__ __align__(16) float redl[128];
  __shared__ __align__(16) float psq[2048];
  __shared__ __align__(16) float redo[512];
  const int blk = blockIdx.x, tid = threadIdx.x;
  const int pc = t & 1, pp = pc ^ 1;
  uint_t* XC0 = (uint_t*)(ws + OFF_XC0);
  uint_t* XC1 = (uint_t*)(ws + OFF_XC1);
  float* ATTC = ws + OFF_ATTC;

  if (blk >= 32){
    // -------- output GEMV for step tt = t-2 --------
    if (t < 2) return;
    const int tt = t - 2;
    int ob = blk - 32;                 // 0..23
    int b = tid & 31, rr = (tid>>5)&3, ksq = tid>>7;
    int r = ob*4 + rr;                 // 0..95
    const float* wr = (r < 80) ? (featw + (size_t)r*1536) : probw;
    const float* acp = ATTC + (size_t)(tt%3)*16384 + b*512;
    float acc = 0.f;
    for (int j=0;j<96;j++){
      int k = ksq*384 + j*4;
      float x0,x1,x2,x3;
      if (k < 1024){
        uint2 hw = *(const uint2*)(XC1 + b*1024 + pc*512 + (k>>1));
        half2_t ha = __builtin_bit_cast(half2_t, hw.x);
        half2_t hb = __builtin_bit_cast(half2_t, hw.y);
        x0 = (float)ha[0]; x1 = (float)ha[1]; x2 = (float)hb[0]; x3 = (float)hb[1];
      } else {
        float4 f = *(const float4*)(acp + (k-1024));
        x0 = f.x; x1 = f.y; x2 = f.z; x3 = f.w;
      }
      if (r <= 80){
        float4 wv = *(const float4*)(wr + k);
        acc += wv.x*x0 + wv.y*x1 + wv.z*x2 + wv.w*x3;
      }
    }
    redo[(rr*4+ksq)*32 + b] = acc;
    __syncthreads();
    if (tid < 128){
      int b2 = tid&31, r2 = tid>>5;
      float vsum = redo[(r2*4+0)*32+b2] + redo[(r2*4+1)*32+b2]
                 + redo[(r2*4+2)*32+b2] + redo[(r2*4+3)*32+b2];
      int rr2 = ob*4 + r2;
      if (rr2 < 80)       out[((size_t)b2*80 + rr2)*256 + tt] = vsum;
      else if (rr2 == 80) out[LOG_OFF + (size_t)b2*256 + tt] = vsum + probb[0];
    }
    return;
  }

  // -------- attention for batch b = blk --------
  if (t >= TD_) return;
  const int b = blk;
  const int len = lens[b];
  const float* PM = ws + OFF_PM;
  const float* Mg = ws + OFF_M;
  const uint_t* WWH = (const uint_t*)(ws + OFF_WWH);
  const uint_t* ENCH = (const uint_t*)(ws + OFF_ENCH);
  const uint_t* P1H = (const uint_t*)(ws + OFF_P1H);
  float* CUM = ws + OFF_CUM;

  if (tid < 128)
    *(uint4*)(h0l + tid*4) = *(const uint4*)(XC0 + b*1408 + 384 + pp*512 + tid*4);
  for (int i=tid; i<128*31; i+=512) Ml[(i/31)*32 + (i%31)] = Mg[i];
  for (int i=tid; i<288; i+=512){
    int p = i - 15;
    float vv = 0.f;
    if (p >= 0 && p < 256)
      vv = (t==0) ? ((p < len) ? 1.0f/(float)len : 0.f) : CUM[b*256 + p];
    apad[i] = vv;
  }
  if (tid < 128) wl[tid] = ww[tid];
  __syncthreads();
  // ---- Wh = Ww . h0(t-1), fp16 dot2 ----
  {
    int ag = tid >> 4, l16 = tid & 15;
    float wv0=0, wv1=0, wv2=0, wv3=0;
    for (int q=0;q<32;q++){
      uint_t xv = h0l[l16 + q*16];
      wv0 = dot2f(WWH[(ag*4+0)*512 + l16 + q*16], xv, wv0);
      wv1 = dot2f(WWH[(ag*4+1)*512 + l16 + q*16], xv, wv1);
      wv2 = dot2f(WWH[(ag*4+2)*512 + l16 + q*16], xv, wv2);
      wv3 = dot2f(WWH[(ag*4+3)*512 + l16 + q*16], xv, wv3);
    }
    float v0, v1;
    { bool up = (l16 & 8) != 0;
      float g0 = up ? wv0 : wv2, k0 = up ? wv2 : wv0;
      float g1 = up ? wv1 : wv3, k1 = up ? wv3 : wv1;
      v0 = k0 + __shfl_xor(g0, 8);
      v1 = k1 + __shfl_xor(g1, 8); }
    { bool up = (l16 & 4) != 0;
      float g = up ? v0 : v1, k = up ? v1 : v0;
      v0 = k + __shfl_xor(g, 4); }
    v0 += __shfl_xor(v0, 2);
    v0 += __shfl_xor(v0, 1);
    if ((l16 & 3) == 0) whl[ag*4 + (l16>>2)] = v0;
  }
  __syncthreads();
  // ---- scores ----
  {
    int pg = tid & 63, q = tid >> 6;
    float apw[36];
    #pragma unroll
    for (int i=0;i<36;i+=4) *(float4*)&apw[i] = *(const float4*)&apad[pg*4 + i];
    float part0=0, part1=0, part2=0, part3=0;
    const float* pmb = PM + (size_t)b*128*256;
    for (int aa=0; aa<16; aa++){
      int a = q*16 + aa;
      const float* mr = Ml + a*32;
      float4 pv = *(const float4*)(pmb + (size_t)a*256 + pg*4);
      float wa = whl[a];
      float u0 = pv.x + wa, u1 = pv.y + wa, u2 = pv.z + wa, u3 = pv.w + wa;
      #pragma unroll
      for (int k=0;k<28;k+=4){
        float4 m4 = *(const float4*)(mr + k);
        u0 += m4.x*apw[k]   + m4.y*apw[k+1] + m4.z*apw[k+2] + m4.w*apw[k+3];
        u1 += m4.x*apw[k+1] + m4.y*apw[k+2] + m4.z*apw[k+3] + m4.w*apw[k+4];
        u2 += m4.x*apw[k+2] + m4.y*apw[k+3] + m4.z*apw[k+4] + m4.w*apw[k+5];
        u3 += m4.x*apw[k+3] + m4.y*apw[k+4] + m4.z*apw[k+5] + m4.w*apw[k+6];
      }
      float m28 = mr[28], m29 = mr[29], m30 = mr[30];
      u0 += m28*apw[28] + m29*apw[29] + m30*apw[30];
      u1 += m28*apw[29] + m29*apw[30] + m30*apw[31];
      u2 += m28*apw[30] + m29*apw[31] + m30*apw[32];
      u3 += m28*apw[31] + m29*apw[32] + m30*apw[33];
      float wv = wl[a];
      part0 += tanh_f(u0)*wv; part1 += tanh_f(u1)*wv;
      part2 += tanh_f(u2)*wv; part3 += tanh_f(u3)*wv;
    }
    float4 pp2; pp2.x = part0; pp2.y = part1; pp2.z = part2; pp2.w = part3;
    *(float4*)&psq[tid*4] = pp2;
  }
  __syncthreads();
  if (tid < 256){
    float s = wb[0];
    int pgg = tid >> 2, d = tid & 3;
    #pragma unroll
    for (int qq=0;qq<8;qq++) s += psq[(qq*64 + pgg)*4 + d];
    scl[tid] = (tid >= len) ? -1.0e9f : s;
  }
  __syncthreads();
  if (tid < 128) redl[tid] = fmaxf(scl[tid], scl[tid+128]);
  __syncthreads();
  if (tid < 64){
    float v = fmaxf(redl[tid], redl[tid+64]);
    #pragma unroll
    for (int off=32; off>0; off>>=1) v = fmaxf(v, __shfl_down(v, off));
    if (tid==0) redl[0] = v;
  }
  __syncthreads();
  float mx = redl[0];
  if (tid < 256) awl[tid] = __expf(scl[tid]-mx);
  __syncthreads();
  if (tid < 128) redl[tid] = awl[tid] + awl[tid+128];
  __syncthreads();
  if (tid < 64){
    float v = redl[tid] + redl[tid+64];
    #pragma unroll
    for (int off=32; off>0; off>>=1) v += __shfl_down(v, off);
    if (tid==0) redl[0] = v;
  }
  __syncthreads();
  float inv = rcp_f(redl[0]);
  if (tid < 256){
    float aw = awl[tid]*inv;
    awl[tid] = aw;
    CUM[b*256 + tid] += aw;
    out[ATTW_OFF + ((size_t)b*TD_ + t)*256 + tid] = aw;
  }
  __syncthreads();
  // ---- context (fp16 enc) ----
  {
    int el = tid & 127, ph = tid >> 7;
    const uint_t* ep = ENCH + ((size_t)b*256 + ph*64)*256 + el*2;
    float c0=0,c1=0,c2=0,c3=0;
    for (int p=0;p<64;p++){
      float a = awl[ph*64 + p];
      uint2 ev = *(const uint2*)(ep + (size_t)p*256);
      half2_t h0v = __builtin_bit_cast(half2_t, ev.x);
      half2_t h1v = __builtin_bit_cast(half2_t, ev.y);
      c0 += a*(float)h0v[0]; c1 += a*(float)h0v[1];
      c2 += a*(float)h1v[0]; c3 += a*(float)h1v[1];
    }
    float4 ca; ca.x=c0; ca.y=c1; ca.z=c2; ca.w=c3;
    *(float4*)&psq[(ph*128 + el)*4] = ca;
  }
  __syncthreads();
  if (tid < 128){
    float4 s = *(const float4*)&psq[tid*4];
    #pragma unroll
    for (int g=1; g<4; g++){
      float4 o = *(const float4*)&psq[(g*128+tid)*4];
      s.x+=o.x; s.y+=o.y; s.z+=o.z; s.w+=o.w;
    }
    *(float4*)(ATTC + (size_t)(t%3)*16384 + b*512 + tid*4) = s;
    XC0[b*1408 + tid*2]     = packh2(s.x, s.y);
    XC0[b*1408 + tid*2 + 1] = packh2(s.z, s.w);
    XC0[b*1408 + 256 + tid] = P1H[((size_t)t*32 + b)*128 + tid];
  }
}

// ---------------- per-step kernel B: lstm0(t) + lstm1(t-1) ----------------

__global__ __launch_bounds__(512, 1) void k_stepb(int t,
    const float* __restrict__ l0bih, const float* __restrict__ l0bhh,
    const float* __restrict__ l1bih, const float* __restrict__ l1bhh,
    float* __restrict__ ws){
  __shared__ __align__(16) uint_t smem[36992];   // xl (<=32896) + gsum 4096
  float* gs = (float*)(smem + 32896);
  const int tid = threadIdx.x;
  const int pc = t & 1, pp = pc ^ 1;
  const int bp = tid & 15, ul = (tid>>4)&3, kq = tid >> 6;
  const int seg = tid & 15, bq = tid >> 4;
  const int u0 = blockIdx.x*4;
  uint_t* XC0 = (uint_t*)(ws + OFF_XC0);
  uint_t* XC1 = (uint_t*)(ws + OFF_XC1);
  _Float16* XC0h = (_Float16*)XC0;
  _Float16* XC1h = (_Float16*)XC1;
  float* C0 = ws + OFF_C0;
  float* C1 = ws + OFF_C1;
  const uint_t* W0P = (const uint_t*)(ws + OFF_W0P);
  const uint_t* W1P = (const uint_t*)(ws + OFF_W1P);

  // ======== phase 1: lstm0(t) ========
  if (t < TD_){
    const uint_t* xsrc = XC0 + bq*1408;
    uint_t* xdst = smem + bq*900;
    #pragma unroll
    for (int q=0;q<14;q++){
      int off = (seg + q*16)*4;
      uint4 v;
      if (off < 384) v = *(const uint4*)(xsrc + off);
      else           v = *(const uint4*)(xsrc + 384 + pp*512 + (off-384));
      *(uint4*)(xdst + off) = v;
    }
  }
  __syncthreads();
  if (t < TD_){
    const uint4* xa = (const uint4*)(smem + bp*900 + kq*112);
    const uint4* xb = (const uint4*)(smem + (bp+16)*900 + kq*112);
    const uint4* w4 = (const uint4*)W0P;
    const int rb = (u0 + ul)*224 + kq*28;      // g stride = 1024*224
    float a00=0,a01=0,a02=0,a03=0, a10=0,a11=0,a12=0,a13=0;
    #pragma unroll 4
    for (int i=0;i<28;i++){
      uint4 xva = xa[i], xvb = xb[i];
      uint4 w0 = w4[rb + 0*229376 + i];
      uint4 w1 = w4[rb + 1*229376 + i];
      uint4 w2 = w4[rb + 2*229376 + i];
      uint4 w3 = w4[rb + 3*229376 + i];
      a00=dot2f(w0.x,xva.x,a00); a00=dot2f(w0.y,xva.y,a00); a00=dot2f(w0.z,xva.z,a00); a00=dot2f(w0.w,xva.w,a00);
      a10=dot2f(w0.x,xvb.x,a10); a10=dot2f(w0.y,xvb.y,a10); a10=dot2f(w0.z,xvb.z,a10); a10=dot2f(w0.w,xvb.w,a10);
      a01=dot2f(w1.x,xva.x,a01); a01=dot2f(w1.y,xva.y,a01); a01=dot2f(w1.z,xva.z,a01); a01=dot2f(w1.w,xva.w,a01);
      a11=dot2f(w1.x,xvb.x,a11); a11=dot2f(w1.y,xvb.y,a11); a11=dot2f(w1.z,xvb.z,a11); a11=dot2f(w1.w,xvb.w,a11);
      a02=dot2f(w2.x,xva.x,a02); a02=dot2f(w2.y,xva.y,a02); a02=dot2f(w2.z,xva.z,a02); a02=dot2f(w2.w,xva.w,a02);
      a12=dot2f(w2.x,xvb.x,a12); a12=dot2f(w2.y,xvb.y,a12); a12=dot2f(w2.z,xvb.z,a12); a12=dot2f(w2.w,xvb.w,a12);
      a03=dot2f(w3.x,xva.x,a03); a03=dot2f(w3.y,xva.y,a03); a03=dot2f(w3.z,xva.z,a03); a03=dot2f(w3.w,xva.w,a03);
      a13=dot2f(w3.x,xvb.x,a13); a13=dot2f(w3.y,xvb.y,a13); a13=dot2f(w3.z,xvb.z,a13); a13=dot2f(w3.w,xvb.w,a13);
    }
    int base = ((kq*4 + ul)*4);
    gs[(base+0)*32 + bp] = a00; gs[(base+0)*32 + bp+16] = a10;
    gs[(base+1)*32 + bp] = a01; gs[(base+1)*32 + bp+16] = a11;
    gs[(base+2)*32 + bp] = a02; gs[(base+2)*32 + bp+16] = a12;
    gs[(base+3)*32 + bp] = a03; gs[(base+3)*32 + bp+16] = a13;
  }
  __syncthreads();
  // cell update lstm0 (tid<128) + stage phase-2 x concurrently
  if (t < TD_ && tid < 128){
    int b = tid & 31, uu = tid >> 5;
    int u = u0 + uu;
    float g4[4];
    #pragma unroll
    for (int g=0; g<4; g++){
      float s = 0.f;
      #pragma unroll
      for (int k2=0;k2<8;k2++) s += gs[((k2*4+uu)*4 + g)*32 + b];
      g4[g] = s + l0bih[g*1024+u] + l0bhh[g*1024+u];
    }
    float c_old = C0[u*32 + b];
    float h_old = (float)XC0h[b*2816 + 768 + pp*1024 + u];
    float cn = sigm(g4[1])*c_old + sigm(g4[0])*tanh_f(g4[2]);
    float hn = sigm(g4[3])*tanh_f(cn);
    C0[u*32 + b] = 0.1f*c_old + 0.9f*cn;
    XC0h[b*2816 + 768 + pc*1024 + u] = (_Float16)(0.1f*h_old + 0.9f*hn);
  }

  // ======== phase 2: lstm1(t-1) ========
  if (t >= 1){
    {
      uint_t* xdst = smem + bq*1028;
      #pragma unroll
      for (int q=0;q<16;q++){
        int off = (seg + q*16)*4;
        uint4 v;
        if (off < 512) v = *(const uint4*)(XC0 + bq*1408 + 384 + pp*512 + off);
        else           v = *(const uint4*)(XC1 + bq*1024 + pc*512 + (off-512));
        *(uint4*)(xdst + off) = v;
      }
    }
    __syncthreads();
    {
      const uint4* xa = (const uint4*)(smem + bp*1028 + kq*128);
      const uint4* xb = (const uint4*)(smem + (bp+16)*1028 + kq*128);
      const uint4* w4 = (const uint4*)W1P;
      const int rb = (u0 + ul)*256 + kq*32;    // g stride = 1024*256
      float a00=0,a01=0,a02=0,a03=0, a10=0,a11=0,a12=0,a13=0;
      #pragma unroll 4
      for (int i=0;i<32;i++){
        uint4 xva = xa[i], xvb = xb[i];
        uint4 w0 = w4[rb + 0*262144 + i];
        uint4 w1 = w4[rb + 1*262144 + i];
        uint4 w2 = w4[rb + 2*262144 + i];
        uint4 w3 = w4[rb + 3*262144 + i];
        a00=dot2f(w0.x,xva.x,a00); a00=dot2f(w0.y,xva.y,a00); a00=dot2f(w0.z,xva.z,a00); a00=dot2f(w0.w,xva.w,a00);
        a10=dot2f(w0.x,xvb.x,a10); a10=dot2f(w0.y,xvb.y,a10); a10=dot2f(w0.z,xvb.z,a10); a10=dot2f(w0.w,xvb.w,a10);
        a01=dot2f(w1.x,xva.x,a01); a01=dot2f(w1.y,xva.y,a01); a01=dot2f(w1.z,xva.z,a01); a01=dot2f(w1.w,xva.w,a01);
        a11=dot2f(w1.x,xvb.x,a11); a11=dot2f(w1.y,xvb.y,a11); a11=dot2f(w1.z,xvb.z,a11); a11=dot2f(w1.w,xvb.w,a11);
        a02=dot2f(w2.x,xva.x,a02); a02=dot2f(w2.y,xva.y,a02); a02=dot2f(w2.z,xva.z,a02); a02=dot2f(w2.w,xva.w,a02);
        a12=dot2f(w2.x,xvb.x,a12); a12=dot2f(w2.y,xvb.y,a12); a12=dot2f(w2.z,xvb.z,a12); a12=dot2f(w2.w,xvb.w,a12);
        a03=dot2f(w3.x,xva.x,a03); a03=dot2f(w3.y,xva.y,a03); a03=dot2f(w3.z,xva.z,a03); a03=dot2f(w3.w,xva.w,a03);
        a13=dot2f(w3.x,xvb.x,a13); a13=dot2f(w3.y,xvb.y,a13); a13=dot2f(w3.z,xvb.z,a13); a13=dot2f(w3.w,xvb.w,a13);
      }
      int base = ((kq*4 + ul)*4);
      gs[(base+0)*32 + bp] = a00; gs[(base+0)*32 + bp+16] = a10;
      gs[(base+1)*32 + bp] = a01; gs[(base+1)*32 + bp+16] = a11;
      gs[(base+2)*32 + bp] = a02; gs[(base+2)*32 + bp+16] = a12;
      gs[(base+3)*32 + bp] = a03; gs[(base+3)*32 + bp+16] = a13;
    }
    __syncthreads();
    if (tid < 128){
      int b = tid & 31, uu = tid >> 5;
      int u = u0 + uu;
      float g4[4];
      #pragma unroll
      for (int g=0; g<4; g++){
        float s = 0.f;
        #pragma unroll
        for (int k2=0;k2<8;k2++) s += gs[((k2*4+uu)*4 + g)*32 + b];
        g4[g] = s + l1bih[g*1024+u] + l1bhh[g*1024+u];
      }
      float c_old = C1[u*32 + b];
      float h_old = (float)XC1h[b*2048 + pc*1024 + u];   // h1(t-2)
      float cn = sigm(g4[1])*c_old + sigm(g4[0])*tanh_f(g4[2]);
      float hn = sigm(g4[3])*tanh_f(cn);
      C1[u*32 + b] = 0.1f*c_old + 0.9f*cn;
      XC1h[b*2048 + pp*1024 + u] = (_Float16)(0.1f*h_old + 0.9f*hn);  // h1(t-1)
    }
  }
}

extern "C" void kernel_launch(void* const* d_in, const int* in_sizes, int n_in,
                              void* d_out, int out_size, void* d_ws, size_t ws_size,
                              hipStream_t stream){
  const float* enc   = (const float*)d_in[0];
  const float* tgt   = (const float*)d_in[1];
  const float* masks = (const float*)d_in[2];
  const int*   lens  = (const int*)  d_in[3];
  const float* Vw    = (const float*)d_in[4];
  const float* Vb    = (const float*)d_in[5];
  const float* Ww    = (const float*)d_in[6];
  const float* Uw    = (const float*)d_in[7];
  const float* Fw    = (const float*)d_in[8];
  const float* ww    = (const float*)d_in[9];
  const float* wb    = (const float*)d_in[10];
  const float* pw0   = (const float*)d_in[11];
  const float* pb0   = (const float*)d_in[12];
  const float* pw1   = (const float*)d_in[13];
  const float* pb1   = (const float*)d_in[14];
  const float* l0wih = (const float*)d_in[15];
  const float* l0whh = (const float*)d_in[16];
  const float* l0bih = (const float*)d_in[17];
  const float* l0bhh = (const float*)d_in[18];
  const float* l1wih = (const float*)d_in[19];
  const float* l1whh = (const float*)d_in[20];
  const float* l1bih = (const float*)d_in[21];
  const float* l1bhh = (const float*)d_in[22];
  const float* featw = (const float*)d_in[23];
  const float* probw = (const float*)d_in[24];
  const float* probb = (const float*)d_in[25];
  float* ws  = (float*)d_ws;
  float* out = (float*)d_out;

  k_init   <<<256, 256,0,stream>>>(ws);
  k_pre    <<<256, 256,0,stream>>>(tgt, pw0, pb0, pw1, pb1, masks, ws);
  k_precm  <<<1,   256,0,stream>>>(Uw, Fw, ws);
  k_cvtww  <<<128, 256,0,stream>>>(Ww, ws);
  k_packenc<<<8192,256,0,stream>>>(enc, ws);
  k_packw0 <<<4096,256,0,stream>>>(l0wih, l0whh, ws);
  k_packw1 <<<4096,256,0,stream>>>(l1wih, l1whh, ws);
  k_pm     <<<128, 256,0,stream>>>(enc, Vw, Vb, ws);

  for (int t = 0; t < TD_; t++){
    k_stepa<<<56, 512,0,stream>>>(t, lens, ww, wb, featw, probw, probb, ws, out);
    k_stepb<<<256,512,0,stream>>>(t, l0bih, l0bhh, l1bih, l1bhh, ws);
  }
  k_stepb<<<256,512,0,stream>>>(256, l0bih, l0bhh, l1bih, l1bhh, ws);  // lstm1(255)
  k_stepa<<<56, 512,0,stream>>>(256, lens, ww, wb, featw, probw, probb, ws, out); // out(254)
  k_stepa<<<56, 512,0,stream>>>(257, lens, ww, wb, featw, probw, probb, ws, out); // out(255)
}